// Round 4
// baseline (1178.236 us; speedup 1.0000x reference)
//
#include <hip/hip_runtime.h>
#include <hip/hip_bf16.h>
#include <stdint.h>

#define L_ 200
#define SCALE_ 5000000.0f

typedef __attribute__((ext_vector_type(8))) short bf16x8;  // 8 bf16 = 4 VGPR
typedef __attribute__((ext_vector_type(4))) float f32x4;   // MFMA acc

static __device__ __forceinline__ short to_bf16(float f) {
    __hip_bfloat16 h = __float2bfloat16(f);
    return *reinterpret_cast<short*>(&h);
}
static __device__ __forceinline__ float fsig(float x) {
    return __builtin_amdgcn_rcpf(1.0f + __builtin_amdgcn_exp2f(-1.442695041f * x));
}
static __device__ __forceinline__ float ftanh(float x) {
    return 1.0f - 2.0f * __builtin_amdgcn_rcpf(1.0f + __builtin_amdgcn_exp2f(2.885390082f * x));
}

// ---------------------------------------------------------------------------
// Prep: pack weights into bf16 MFMA B-fragment order and fold biases.
// B-frag (16x16x32): lane l holds B[n][k], n=(l&15)+16*tile, k=kt*32+(l>>4)*8+b.
// ---------------------------------------------------------------------------
__global__ void prep_kernel(const float* __restrict__ U_all, const float* __restrict__ W_all,
                            const float* __restrict__ W_d, const float* __restrict__ b_W,
                            const float* __restrict__ b_U, const float* __restrict__ b_d,
                            short* __restrict__ ufrag, short* __restrict__ wfrag,
                            short* __restrict__ wdfrag, float* __restrict__ bias512,
                            float* __restrict__ bdo, int n_total) {
    int i = blockIdx.x * 256 + threadIdx.x;
    if (i >= n_total) return;
    if (i < 131072) {                     // U_all [512][256]
        int b = i & 7, lane = (i >> 3) & 63, kt = (i >> 9) & 7, g = (i >> 12) & 3, w = i >> 14;
        int n = g * 128 + w * 16 + (lane & 15);
        int k = kt * 32 + (lane >> 4) * 8 + b;
        ufrag[i] = to_bf16(U_all[n * 256 + k]);
    } else if (i < 196608) {              // W_all [512][128]
        int j = i - 131072;
        int b = j & 7, lane = (j >> 3) & 63, kt = (j >> 9) & 3, g = (j >> 11) & 3, w = j >> 13;
        int n = g * 128 + w * 16 + (lane & 15);
        int k = kt * 32 + (lane >> 4) * 8 + b;
        wfrag[j] = to_bf16(W_all[n * 128 + k]);
    } else if (i < 212992) {              // W_d [128][128]
        int m = i - 196608;
        int b = m & 7, lane = (m >> 3) & 63, kt = (m >> 9) & 3, w = m >> 11;
        int n = w * 16 + (lane & 15);
        int k = kt * 32 + (lane >> 4) * 8 + b;
        wdfrag[m] = to_bf16(W_d[n * 128 + k]);
    } else if (i < 213504) {
        int n = i - 212992;
        bias512[n] = b_W[n] + b_U[n];
    } else {
        int n = i - 213504;
        bdo[n] = b_d[n];
    }
}

// ---------------------------------------------------------------------------
// Fused TimeLSTM v3: u_t computed in-step via MFMA (x@U^T, K=256) on the
// otherwise-idle matrix pipe; rec-style single barrier per step with
// double-buffered A-frag h/c in LDS. 128 blocks x 512 thr, 16 REAL rows per
// block (no quad duplication). x_{t+1} register-prefetched a full step
// (~3350 cy) ahead of use. All LDS frag reads are stride-1 conflict-free.
// Eliminates the 419 MB u workspace round-trip and the separate GEMM kernel.
// ---------------------------------------------------------------------------
__global__ __launch_bounds__(512, 2) void fused_kernel(
    const float* __restrict__ seq, const float* __restrict__ seq_e,
    const float* __restrict__ time_diff,
    const short* __restrict__ ufrag, const short* __restrict__ wfrag,
    const short* __restrict__ wdfrag, const float* __restrict__ bias512,
    const float* __restrict__ bdv, float* __restrict__ hn_buf) {

    __shared__ __align__(16) short xf[2][8][512];   // 16 KB: dbuf x A-frags (K=256)
    __shared__ __align__(16) short hf[2][2048];     //  8 KB: dbuf h A-frags (K=128)
    __shared__ __align__(16) short cf[2][2048];     //  8 KB: dbuf c A-frags
    __shared__ float tspan[16 * 201];               // 12.9 KB

    const int tid = threadIdx.x;
    const int w = tid >> 6, lane = tid & 63;
    const int col16 = lane & 15, quad = lane >> 4;
    const int row0 = quad * 4;
    const int b0 = blockIdx.x * 16;

    // register-resident B-frags: x@U (4 gg x 8 kt), h@W (4 x 4), c@Wd (4)
    bf16x8 uB[4][8], wB[4][4], wd[4];
#pragma unroll
    for (int g = 0; g < 4; ++g)
#pragma unroll
        for (int kt = 0; kt < 8; ++kt)
            uB[g][kt] = ((const bf16x8*)ufrag)[((w * 4 + g) * 8 + kt) * 64 + lane];
#pragma unroll
    for (int g = 0; g < 4; ++g)
#pragma unroll
        for (int kt = 0; kt < 4; ++kt)
            wB[g][kt] = ((const bf16x8*)wfrag)[((w * 4 + g) * 4 + kt) * 64 + lane];
#pragma unroll
    for (int kt = 0; kt < 4; ++kt)
        wd[kt] = ((const bf16x8*)wdfrag)[(w * 4 + kt) * 64 + lane];

    float bs[4];
#pragma unroll
    for (int g = 0; g < 4; ++g) bs[g] = bias512[g * 128 + w * 16 + col16];
    const float bd = bdv[w * 16 + col16];

    // time spans for this block's 16 rows
    for (int i = tid; i < 16 * L_; i += 512) {
        int r = i / L_, t = i - r * L_;
        float v = 0.0f;
        if (t > 0) {
            const float* td = time_diff + (size_t)(b0 + r) * L_;
            v = (td[t - 1] - td[t]) * (1.0f / SCALE_);
        }
        tspan[r * 201 + t] = v;
    }
    for (int i = tid; i < 2048; i += 512) {
        hf[0][i] = 0; hf[1][i] = 0; cf[0][i] = 0; cf[1][i] = 0;
    }

    // h/c write offset: element (row m, col=w*16+col16) in A-frag layout:
    // flat = (k>>5)*512 + ((k>>3)&3)*128 + m*8 + (k&7), k = w*16+col16
    const int kto = (w >> 1) * 512 + ((w & 1) * 2 + (col16 >> 3)) * 128 + (col16 & 7);

    // x source: row = b0+col16, k-chunk = w*32 + quad*8 (8 fp32 = 32 B/thread)
    const int kb = w * 32 + quad * 8;
    const float* xsrc = (kb < 128)
        ? (seq   + (size_t)(b0 + col16) * L_ * 128 + kb)
        : (seq_e + (size_t)(b0 + col16) * L_ * 128 + (kb - 128));

    // stage x_0 into buffer 0
    {
        const float4* p = (const float4*)xsrc;
        float4 a0 = p[0], a1 = p[1];
        bf16x8 sv;
        sv[0] = to_bf16(a0.x); sv[1] = to_bf16(a0.y); sv[2] = to_bf16(a0.z); sv[3] = to_bf16(a0.w);
        sv[4] = to_bf16(a1.x); sv[5] = to_bf16(a1.y); sv[6] = to_bf16(a1.z); sv[7] = to_bf16(a1.w);
        ((bf16x8*)xf[0][w])[lane] = sv;
    }
    __syncthreads();

    f32x4 cacc = {0.f, 0.f, 0.f, 0.f};
    float hreg[4] = {0.f, 0.f, 0.f, 0.f};
    int par = 0;

    for (int t = 0; t < L_; ++t) {
        // prefetch x_{t+1} (consumed at end of step — full step of latency cover)
        int tt = (t + 1 < L_) ? (t + 1) : (L_ - 1);
        const float4* p = (const float4*)(xsrc + (size_t)tt * 128);
        float4 nx0 = p[0], nx1 = p[1];

        // gates = bias + x_t@U^T + h@W^T  (accumulated in f32 MFMA)
        f32x4 acc[4];
#pragma unroll
        for (int g = 0; g < 4; ++g) acc[g] = (f32x4){bs[g], bs[g], bs[g], bs[g]};
#pragma unroll
        for (int kt = 0; kt < 8; ++kt) {
            bf16x8 a = ((const bf16x8*)xf[par][kt])[lane];
#pragma unroll
            for (int g = 0; g < 4; ++g)
                acc[g] = __builtin_amdgcn_mfma_f32_16x16x32_bf16(a, uB[g][kt], acc[g], 0, 0, 0);
        }
#pragma unroll
        for (int kt = 0; kt < 4; ++kt) {
            bf16x8 a = ((const bf16x8*)hf[par])[kt * 64 + lane];
#pragma unroll
            for (int g = 0; g < 4; ++g)
                acc[g] = __builtin_amdgcn_mfma_f32_16x16x32_bf16(a, wB[g][kt], acc[g], 0, 0, 0);
        }
        f32x4 cs = {bd, bd, bd, bd};
#pragma unroll
        for (int kt = 0; kt < 4; ++kt) {
            bf16x8 a = ((const bf16x8*)cf[par])[kt * 64 + lane];
            cs = __builtin_amdgcn_mfma_f32_16x16x32_bf16(a, wd[kt], cs, 0, 0, 0);
        }

        // gate math + write h/c for t+1 into the other buffer
#pragma unroll
        for (int r = 0; r < 4; ++r) {
            float ttv = tspan[(row0 + r) * 201 + t];
            float f   = fsig(acc[0][r]);
            float i_  = fsig(acc[1][r]);
            float o   = fsig(acc[2][r]);
            float g4  = fsig(acc[3][r]);
            float cs1 = ftanh(cs[r]);
            float ca  = cacc[r] - cs1 + cs1 * ttv;
            float cn  = f * ca + i_ * g4;
            float hv  = o * ftanh(cn);
            cacc[r] = cn;
            hreg[r] = hv;
            hf[par ^ 1][kto + (row0 + r) * 8] = to_bf16(hv);
            cf[par ^ 1][kto + (row0 + r) * 8] = to_bf16(cn);
        }
        // stage prefetched x_{t+1}
        {
            bf16x8 sv;
            sv[0] = to_bf16(nx0.x); sv[1] = to_bf16(nx0.y); sv[2] = to_bf16(nx0.z); sv[3] = to_bf16(nx0.w);
            sv[4] = to_bf16(nx1.x); sv[5] = to_bf16(nx1.y); sv[6] = to_bf16(nx1.z); sv[7] = to_bf16(nx1.w);
            ((bf16x8*)xf[par ^ 1][w])[lane] = sv;
        }
        __syncthreads();
        par ^= 1;
    }

#pragma unroll
    for (int r = 0; r < 4; ++r)
        hn_buf[(size_t)(b0 + row0 + r) * 128 + w * 16 + col16] = hreg[r];
}

// ---------------------------------------------------------------------------
// Merge: out = fc2( relu( fc1( [hn, src] ) ) ), in-place over d_out.
// ---------------------------------------------------------------------------
__global__ __launch_bounds__(256) void merge_kernel(
    const float* __restrict__ src, const float* __restrict__ fc1w,
    const float* __restrict__ fc1b, const float* __restrict__ fc2w,
    const float* __restrict__ fc2b, float* __restrict__ out) {
    __shared__ float xc[16][256];
    __shared__ float hm[16][128];
    const int tid = threadIdx.x;
    const int b0 = blockIdx.x * 16;
    for (int i = tid; i < 16 * 256; i += 256) {
        int r = i >> 8, k = i & 255;
        xc[r][k] = (k < 128) ? out[(size_t)(b0 + r) * 128 + k]
                             : src[(size_t)(b0 + r) * 128 + (k - 128)];
    }
    __syncthreads();
#pragma unroll
    for (int ii = 0; ii < 8; ++ii) {
        int o = tid + 256 * ii;
        int r = o >> 7, m = o & 127;
        const float4* wr = (const float4*)(fc1w + m * 256);
        const float4* xr = (const float4*)(xc[r]);
        float acc = fc1b[m];
        for (int k4 = 0; k4 < 64; ++k4) {
            float4 a = wr[k4], b = xr[k4];
            acc += a.x * b.x + a.y * b.y + a.z * b.z + a.w * b.w;
        }
        hm[r][m] = fmaxf(acc, 0.0f);
    }
    __syncthreads();
#pragma unroll
    for (int ii = 0; ii < 8; ++ii) {
        int o = tid + 256 * ii;
        int r = o >> 7, j = o & 127;
        const float4* wr = (const float4*)(fc2w + j * 128);
        const float4* xr = (const float4*)(hm[r]);
        float acc = fc2b[j];
        for (int k4 = 0; k4 < 32; ++k4) {
            float4 a = wr[k4], b = xr[k4];
            acc += a.x * b.x + a.y * b.y + a.z * b.z + a.w * b.w;
        }
        out[(size_t)(b0 + r) * 128 + j] = acc;
    }
}

// ---------------------------------------------------------------------------
extern "C" void kernel_launch(void* const* d_in, const int* in_sizes, int n_in,
                              void* d_out, int out_size, void* d_ws, size_t ws_size,
                              hipStream_t stream) {
    const float* src       = (const float*)d_in[0];
    const float* seq       = (const float*)d_in[2];
    const float* seq_e     = (const float*)d_in[4];
    const float* time_diff = (const float*)d_in[5];
    const float* W_all     = (const float*)d_in[7];
    const float* b_W       = (const float*)d_in[8];
    const float* U_all     = (const float*)d_in[9];
    const float* b_U       = (const float*)d_in[10];
    const float* W_d       = (const float*)d_in[11];
    const float* b_d       = (const float*)d_in[12];
    const float* fc1w      = (const float*)d_in[13];
    const float* fc1b      = (const float*)d_in[14];
    const float* fc2w      = (const float*)d_in[15];
    const float* fc2b      = (const float*)d_in[16];

    char* ws = (char*)d_ws;
    short* ufrag   = (short*)(ws);             // 262144 B
    short* wfrag   = (short*)(ws + 262144);    // 131072 B
    short* wdfrag  = (short*)(ws + 393216);    //  32768 B
    float* bias512 = (float*)(ws + 425984);    //   2048 B
    float* bdo     = (float*)(ws + 428032);    //    512 B
    float* outp    = (float*)d_out;

    prep_kernel<<<835, 256, 0, stream>>>(U_all, W_all, W_d, b_W, b_U, b_d,
                                         ufrag, wfrag, wdfrag, bias512, bdo, 213632);
    fused_kernel<<<128, 512, 0, stream>>>(seq, seq_e, time_diff,
                                          ufrag, wfrag, wdfrag, bias512, bdo, outp);
    merge_kernel<<<128, 256, 0, stream>>>(src, fc1w, fc1b, fc2w, fc2b, outp);
}